// Round 15
// baseline (125.972 us; speedup 1.0000x reference)
//
#include <hip/hip_runtime.h>

#define TPB 256

typedef float f32x4 __attribute__((ext_vector_type(4)));

// Chunk = 64 flat slots (one wave's ballot width). chunks = NK/64.
// blockHist[c*E + e] = count of expert e in chunk c (later: global flat prefix).

// Kernel 1: per-chunk expert histogram. 256-thread block = 4 chunks, one per wave.
__global__ void k_hist(const int* __restrict__ eidx, int* __restrict__ blockHist,
                       int NK, int E) {
    __shared__ int hist[4 * 64];
    int tid = threadIdx.x;
    int wv = tid >> 6, lane = tid & 63;
    hist[tid & 255] = 0;                 // 256 slots zeroed
    __syncthreads();
    int j = blockIdx.x * TPB + tid;
    if (j < NK) atomicAdd(&hist[wv * 64 + eidx[j]], 1);
    __syncthreads();
    int c = blockIdx.x * 4 + wv;         // this wave's chunk
    if (lane < E && (size_t)c * 64 < (size_t)NK)
        blockHist[(size_t)c * E + lane] = hist[wv * 64 + lane];
}

// Kernel 2: one block per expert — parallel exclusive scan of that expert's
// per-chunk counts (in place); per-expert total -> counts[e]. Serial chains are
// length numChunks/TPB = 8 (R8 lesson: keep dependent global chains short).
__global__ void k_scan_blocks(int* __restrict__ blockHist, int* __restrict__ counts,
                              int numChunks, int E) {
    __shared__ int s[TPB];
    int e = blockIdx.x;
    int tid = threadIdx.x;
    int per = (numChunks + TPB - 1) / TPB;
    int start = tid * per;
    int end = start + per; if (end > numChunks) end = numChunks;
    int sum = 0;
    for (int b = start; b < end; ++b) sum += blockHist[(size_t)b * E + e];
    s[tid] = sum;
    __syncthreads();
    for (int off = 1; off < TPB; off <<= 1) {
        int t = (tid >= off) ? s[tid - off] : 0;
        __syncthreads();
        s[tid] += t;
        __syncthreads();
    }
    int run = (tid == 0) ? 0 : s[tid - 1];
    if (tid == TPB - 1) counts[e] = s[tid];
    for (int b = start; b < end; ++b) {
        size_t idx = (size_t)b * E + e;
        int v = blockHist[idx];
        blockHist[idx] = run;
        run += v;
    }
}

// Kernel 3: FUSED pos + scatter. ONE WAVE PER TOKEN, no barriers, no LDS.
// 256-thread block = 4 independent waves = 4 tokens -> 32 tokens in flight/CU.
// Wave for token tok (chunk c = tok*K/64, sub s): lane ranks slot c*64+lane via
// 6-ballot match-any (E<=64); cross-expert offsets via shfl_up scan of counts;
// chunk base via coalesced blockHist load + shfl. Then NT-scatter the row.
// Assumes E <= 64, K divides 64 (here E=64, K=8).
__global__ void __launch_bounds__(TPB) k_pos_scatter(
        const int* __restrict__ eidx, const float* __restrict__ scale,
        const int* __restrict__ blockHist, const int* __restrict__ counts,
        const float* __restrict__ x,
        float* __restrict__ row_idx_out, float* __restrict__ scale_out,
        float* __restrict__ cumsum_out, float* __restrict__ out_x,
        int NK, int E, int K, int H, int N) {
    int tid  = threadIdx.x;
    int wv   = tid >> 6;
    int lane = tid & 63;
    int tok  = blockIdx.x * 4 + wv;
    if (tok >= N) return;
    int spw  = 64 / K;                   // tokens (sub-slots) per wave-chunk
    int c    = tok / spw;                // chunk of 64 flat slots
    int s    = tok - c * spw;            // my token's position within the chunk

    // issue x-row loads early; rank compute hides the latency
    const f32x4* xs = (const f32x4*)(x + (size_t)tok * H);
    int n4 = H >> 2;                     // 256 for H=1024
    f32x4 v0, v1, v2, v3;
    if (lane       < n4) v0 = xs[lane];
    if (lane + 64  < n4) v1 = xs[lane + 64];
    if (lane + 128 < n4) v2 = xs[lane + 128];
    if (lane + 192 < n4) v3 = xs[lane + 192];

    int j = c * 64 + lane;               // flat slot this lane ranks
    bool valid = (j < NK);
    int ei = valid ? eidx[j] : 0;

    // match-any across the wave (E <= 64 -> 6 bits)
    unsigned long long mask = __ballot(valid);
    #pragma unroll
    for (int b = 0; b < 6; ++b) {
        unsigned long long bal = __ballot((ei >> b) & 1);
        mask &= ((ei >> b) & 1) ? bal : ~bal;
    }
    unsigned long long lt = (1ULL << lane) - 1ULL;
    int rank = (int)__popcll(mask & lt);

    // chunk base: coalesced load of blockHist[c][lane], then pick [c][ei]
    int bh = (lane < E) ? blockHist[(size_t)c * E + lane] : 0;
    int base_e = __shfl(bh, ei);

    // cross-expert exclusive offsets: shfl_up inclusive scan of counts[lane]
    int cnt = (lane < E) ? counts[lane] : 0;
    int inc = cnt;
    #pragma unroll
    for (int off = 1; off < 64; off <<= 1) {
        int v = __shfl_up(inc, off);
        if (lane >= off) inc += v;
    }
    int off_e = __shfl(inc - cnt, ei);

    int pos = off_e + base_e + rank;     // stable-sort position of slot j

    // emit cumsum once (token 0's wave)
    if (tok == 0 && lane < E) cumsum_out[lane] = (float)inc;

    // emit row_idx + scale once per chunk (sub-token 0's wave), coalesced by lane
    if (s == 0 && valid) {
        row_idx_out[j] = (float)pos;
        scale_out[pos] = scale[j / K];
    }

    // my token's K destination rows
    int pk[8];
    #pragma unroll
    for (int k = 0; k < 8; ++k)
        if (k < K) pk[k] = __shfl(pos, s * K + k);

    // scatter: plain loads (R10: NT loads cost +15us), NT stores (537MB stream)
    #pragma unroll
    for (int k = 0; k < 8; ++k) {
        if (k < K) {
            f32x4* od = (f32x4*)(out_x + (size_t)pk[k] * H);
            if (lane       < n4) __builtin_nontemporal_store(v0, od + lane);
            if (lane + 64  < n4) __builtin_nontemporal_store(v1, od + lane + 64);
            if (lane + 128 < n4) __builtin_nontemporal_store(v2, od + lane + 128);
            if (lane + 192 < n4) __builtin_nontemporal_store(v3, od + lane + 192);
        }
    }
    // rows longer than 1024 floats: tail (not hit for H=1024)
    for (int t = lane + 256; t < n4; t += 64) {
        f32x4 v = xs[t];
        #pragma unroll
        for (int k = 0; k < 8; ++k)
            if (k < K) __builtin_nontemporal_store(v, (f32x4*)(out_x + (size_t)pk[k] * H) + t);
    }
}

extern "C" void kernel_launch(void* const* d_in, const int* in_sizes, int n_in,
                              void* d_out, int out_size, void* d_ws, size_t ws_size,
                              hipStream_t stream) {
    const float* x     = (const float*)d_in[0];
    const int*   eidx  = (const int*)d_in[1];
    const float* scale = (const float*)d_in[2];

    const int N  = in_sizes[2];            // scale has N elements
    const int H  = in_sizes[0] / N;        // 1024
    const int K  = in_sizes[1] / N;        // 8
    const int NK = N * K;                  // 131072
    const int E  = out_size - (int)((long long)NK * H) - 2 * NK;   // 64

    const int numChunks = (NK + 63) / 64;        // 2048
    const int histBlocks = (NK + TPB - 1) / TPB; // 512

    // d_out layout (all float)
    float* out_x     = (float*)d_out;
    float* out_rowix = out_x + (size_t)NK * H;
    float* out_cum   = out_rowix + NK;
    float* out_scale = out_cum + E;

    // d_ws layout
    int* blockHist = (int*)d_ws;                         // numChunks * E
    int* counts    = blockHist + (size_t)numChunks * E;  // E

    k_hist<<<histBlocks, TPB, 0, stream>>>(eidx, blockHist, NK, E);
    k_scan_blocks<<<E, TPB, 0, stream>>>(blockHist, counts, numChunks, E);
    k_pos_scatter<<<(N + 3) / 4, TPB, 0, stream>>>(eidx, scale, blockHist, counts, x,
                                                   out_rowix, out_scale, out_cum, out_x,
                                                   NK, E, K, H, N);
}